// Round 11
// baseline (333.569 us; speedup 1.0000x reference)
//
#include <hip/hip_runtime.h>
#include <hip/hip_cooperative_groups.h>
#include <hip/hip_bf16.h>
#include <math.h>

namespace cg = cooperative_groups;

#define N_PTS 8192
#define S_PTS 4096
#define TILE 2048
#define CAP 128
typedef unsigned long long u64;
typedef unsigned u32;

// Double-precision pair distance, rounded to float (accurate output values).
__device__ __forceinline__ float pair_dist_d(const float4 a, const float4 b) {
    double ax = a.x, ay = a.y, az = a.z;
    double bx = b.x, by = b.y, bz = b.z;
    double dx = ax - bx, dy = ay - by, dz = az - bz;
    double d2 = dx * dx + dy * dy + dz * dz;
    return d2 > 0.0 ? (float)sqrt(d2) : 0.0f;
}

// Strict fp32 gram-formula d^2 (bit-identical to the reference cdist pipeline).
__device__ __forceinline__ float d2_f32_gram(const float4 a, const float4 b) {
    float dot = __fadd_rn(__fadd_rn(__fmul_rn(a.x, b.x), __fmul_rn(a.y, b.y)),
                          __fmul_rn(a.z, b.z));
    float d2 = __fsub_rn(__fadd_rn(a.w, b.w), __fmul_rn(2.0f, dot));
    return fmaxf(d2, 0.0f);
}

__device__ __forceinline__ u32 bitonic64_u32(u32 v, int lane) {
#pragma unroll
    for (int k = 2; k <= 64; k <<= 1) {
#pragma unroll
        for (int j2 = k >> 1; j2 >= 1; j2 >>= 1) {
            u32 o = __shfl_xor(v, j2, 64);
            bool keepMin = (((lane & j2) == 0) == ((lane & k) == 0));
            bool less = o < v;
            v = keepMin ? (less ? o : v) : (less ? v : o);
        }
    }
    return v;
}

__device__ __forceinline__ u64 bitonic64_u64(u64 v, int lane) {
#pragma unroll
    for (int k = 2; k <= 64; k <<= 1) {
#pragma unroll
        for (int j2 = k >> 1; j2 >= 1; j2 >>= 1) {
            u64 o = __shfl_xor(v, j2, 64);
            bool keepMin = (((lane & j2) == 0) == ((lane & k) == 0));
            bool less = o < v;
            v = keepMin ? (less ? o : v) : (less ? v : o);
        }
    }
    return v;
}

// ---------------------------------------------------------------- stage
__global__ __launch_bounds__(256) void stage_kernel(
        const float* __restrict__ xyz, const int* __restrict__ sidx,
        float4* __restrict__ cb, float4* __restrict__ ca,
        int* __restrict__ inv, float* __restrict__ out_xyz_s) {
    int i = blockIdx.x * blockDim.x + threadIdx.x;
    if (i < N_PTS) {
        float x = xyz[i * 3 + 0], y = xyz[i * 3 + 1], z = xyz[i * 3 + 2];
        float sq = __fadd_rn(__fadd_rn(__fmul_rn(x, x), __fmul_rn(y, y)),
                             __fmul_rn(z, z));
        cb[i] = make_float4(x, y, z, sq);
    }
    if (i < S_PTS) {
        int si = sidx[i];
        float x = xyz[si * 3 + 0], y = xyz[si * 3 + 1], z = xyz[si * 3 + 2];
        float sq = __fadd_rn(__fadd_rn(__fmul_rn(x, x), __fmul_rn(y, y)),
                             __fmul_rn(z, z));
        ca[i] = make_float4(x, y, z, sq);
        inv[si] = i;  // inv pre-set to -1 by hipMemsetAsync(0xFF)
        out_xyz_s[i * 3 + 0] = x;
        out_xyz_s[i * 3 + 1] = y;
        out_xyz_s[i * 3 + 2] = z;
    }
}

// ---------------------------------------------------------------- knn fallbacks
template <int K, bool AFTER>
__device__ u64 cold_ladder(const float4 q, const float4* __restrict__ cb,
                           const int* __restrict__ inv, int lane) {
    u64 L[K];
#pragma unroll
    for (int j = 0; j < K; ++j) L[j] = ~0ull;
    for (int c = lane; c < N_PTS; c += 64) {
        int low = c;
        bool ok = true;
        if (AFTER) { int iv = inv[c]; ok = iv >= 0; low = iv; }
        if (!ok) continue;
        float d2 = d2_f32_gram(q, cb[c]);
        float D = d2 > 0.0f ? __fsqrt_rn(d2) : 0.0f;
        u64 key = ((u64)__float_as_uint(D) << 32) | (u64)(u32)low;
        if (key < L[K - 1]) {
#pragma unroll
            for (int j = K - 1; j >= 1; --j)
                L[j] = (key < L[j - 1]) ? L[j - 1] : ((key < L[j]) ? key : L[j]);
            L[0] = (key < L[0]) ? key : L[0];
        }
    }
    u64 res = ~0ull;
#pragma unroll
    for (int r = 0; r < K; ++r) {
        u64 m = L[0];
#pragma unroll
        for (int off = 32; off >= 1; off >>= 1) {
            u64 o = __shfl_xor(m, off, 64);
            m = (o < m) ? o : m;
        }
        if (lane == r) res = m;
        if (L[0] == m) {
#pragma unroll
            for (int j = 0; j < K - 1; ++j) L[j] = L[j + 1];
            L[K - 1] = ~0ull;
        }
    }
    return res;
}

// sort collected candidates (cnt <= CAP), lane r gets rank r
template <int K>
__device__ u64 finalize_sort(const u64* buf, u32 cnt, int lane) {
    if (cnt <= 64u) {
        u64 v = (lane < (int)cnt) ? buf[lane] : ~0ull;
        return bitonic64_u64(v, lane);
    }
    u64 L0 = ~0ull, L1 = ~0ull, L2 = ~0ull, L3 = ~0ull;
    for (u32 mm = lane; mm < cnt; mm += 64) {
        u64 kk = buf[mm];
        if (kk < L3) {
            if (kk < L1) {
                L3 = L2; L2 = L1;
                if (kk < L0) { L1 = L0; L0 = kk; } else L1 = kk;
            } else {
                if (kk < L2) { L3 = L2; L2 = kk; } else L3 = kk;
            }
        }
    }
    u64 res = ~0ull;
#pragma unroll
    for (int r = 0; r < K; ++r) {
        u64 mr = L0;
#pragma unroll
        for (int off = 32; off >= 1; off >>= 1) {
            u64 o = __shfl_xor(mr, off, 64);
            mr = (o < mr) ? o : mr;
        }
        if (lane == r) res = mr;
        if (L0 == mr) { L0 = L1; L1 = L2; L2 = L3; L3 = ~0ull; }
    }
    return res;
}

// ---------------------------------------------------------------- knn: 8 queries/block, LDS-tiled scan
// Selection exact by (fp32-gram D, idx); tau = K-th smallest of 64 folded
// per-thread minima (provable superset bound, partition-independent).
__global__ __launch_bounds__(256, 2) void knn_kernel(
        const float4* __restrict__ cb, const float4* __restrict__ ca,
        const int* __restrict__ inv, const int* __restrict__ sidx,
        int* __restrict__ a_before, float* __restrict__ intra_before,
        int* __restrict__ ni_i, float* __restrict__ intra_after,
        float* __restrict__ out_ni) {
    __shared__ float4 tile[TILE];        // 32 KB
    __shared__ int tinv[TILE];           // 8 KB
    __shared__ u32 sminT[2][8][256];     // 16 KB
    __shared__ u32 staus[2][8];
    __shared__ u32 scnt[2][8];
    __shared__ u64 sbuf[2][8][CAP];      // 16 KB
    __shared__ float4 sq[8];

    int t = threadIdx.x, lane = t & 63, wid = t >> 6;
    int s0 = blockIdx.x * 8;
    if (t < 8) sq[t] = cb[sidx[s0 + t]];
    if (t < 16) scnt[t >> 3][t & 7] = 0;
    __syncthreads();
    float4 q[8];
#pragma unroll
    for (int i = 0; i < 8; ++i) q[i] = sq[i];

    u32 mB[8], mA[8];
#pragma unroll
    for (int i = 0; i < 8; ++i) { mB[i] = ~0u; mA[i] = ~0u; }

    // pass 1: minima
    for (int tb = 0; tb < N_PTS; tb += TILE) {
        __syncthreads();
        for (int i = t; i < TILE; i += 256) { tile[i] = cb[tb + i]; tinv[i] = inv[tb + i]; }
        __syncthreads();
#pragma unroll
        for (int jj = 0; jj < TILE / 256; ++jj) {
            int li = t + jj * 256;
            float4 p = tile[li];
            bool smp = tinv[li] >= 0;
#pragma unroll
            for (int i = 0; i < 8; ++i) {
                u32 b = __float_as_uint(d2_f32_gram(q[i], p));
                mB[i] = b < mB[i] ? b : mB[i];
                if (smp) mA[i] = b < mA[i] ? b : mA[i];
            }
        }
    }
#pragma unroll
    for (int i = 0; i < 8; ++i) { sminT[0][i][t] = mB[i]; sminT[1][i][t] = mA[i]; }
    __syncthreads();
    // taus: wave w handles streams st = w + 4m  (st<8: before K=4; st>=8: after K=16)
    for (int m = 0; m < 4; ++m) {
        int st = wid + m * 4;
        int k = st >> 3, qi = st & 7;
        u32 v = sminT[k][qi][lane];
        u32 v2 = sminT[k][qi][lane + 64];  v = v2 < v ? v2 : v;
        v2 = sminT[k][qi][lane + 128];     v = v2 < v ? v2 : v;
        v2 = sminT[k][qi][lane + 192];     v = v2 < v ? v2 : v;
        v = bitonic64_u32(v, lane);
        int kk = (k == 0) ? 3 : 15;
        if (lane == kk) staus[k][qi] = v;
    }
    __syncthreads();
    u32 tB[8], tA[8];
#pragma unroll
    for (int i = 0; i < 8; ++i) { tB[i] = staus[0][i]; tA[i] = staus[1][i]; }

    // pass 2: collect qualifiers (sparse LDS atomics, ~0.4% rate)
    for (int tb = 0; tb < N_PTS; tb += TILE) {
        __syncthreads();
        for (int i = t; i < TILE; i += 256) { tile[i] = cb[tb + i]; tinv[i] = inv[tb + i]; }
        __syncthreads();
#pragma unroll
        for (int jj = 0; jj < TILE / 256; ++jj) {
            int li = t + jj * 256;
            float4 p = tile[li];
            int iv = tinv[li];
            bool smp = iv >= 0;
            int c = tb + li;
#pragma unroll
            for (int i = 0; i < 8; ++i) {
                u32 b = __float_as_uint(d2_f32_gram(q[i], p));
                bool qb = b <= tB[i];
                bool qa = smp && (b <= tA[i]);
                if (qb || qa) {
                    float d2v = __uint_as_float(b);
                    float D = d2v > 0.0f ? __fsqrt_rn(d2v) : 0.0f;
                    u64 hk = (u64)__float_as_uint(D) << 32;
                    if (qb) {
                        u32 pos = atomicAdd(&scnt[0][i], 1u);
                        if (pos < CAP) sbuf[0][i][pos] = hk | (u64)(u32)c;
                    }
                    if (qa) {
                        u32 pos = atomicAdd(&scnt[1][i], 1u);
                        if (pos < CAP) sbuf[1][i][pos] = hk | (u64)(u32)iv;
                    }
                }
            }
        }
    }
    __syncthreads();
    // sorts + outputs: wave w handles streams w+4m
    for (int m = 0; m < 4; ++m) {
        int st = wid + m * 4;
        int k = st >> 3, qi = st & 7;
        int s = s0 + qi;
        u32 cnt = scnt[k][qi];
        float4 qq = q[qi];
        if (k == 0) {
            u64 res = (cnt <= CAP) ? finalize_sort<4>(sbuf[0][qi], cnt, lane)
                                   : cold_ladder<4, false>(qq, cb, inv, lane);
            int idx = (int)(res & 0xffffffffull);
            if (lane < 4) a_before[s * 4 + lane] = idx;
            if (lane >= 1 && lane < 4)
                intra_before[s * 6 + (lane - 1)] = pair_dist_d(qq, cb[idx]);
            int i1 = __shfl(idx, 1, 64);
            int i2 = __shfl(idx, 2, 64);
            int i3 = __shfl(idx, 3, 64);
            if (lane < 3) {  // pairs (1,2),(1,3),(2,3)
                int pa = (lane == 2) ? i2 : i1;
                int pb = (lane == 0) ? i2 : i3;
                intra_before[s * 6 + 3 + lane] = pair_dist_d(cb[pa], cb[pb]);
            }
        } else {
            u64 res = (cnt <= CAP) ? finalize_sort<16>(sbuf[1][qi], cnt, lane)
                                   : cold_ladder<16, true>(qq, cb, inv, lane);
            int idx = (int)(res & 0xffffffffull);
            if (lane < 16) {
                ni_i[s * 16 + lane] = idx;
                out_ni[s * 16 + lane] = (float)idx;
            }
            if (lane >= 1 && lane < 4)
                intra_after[s * 6 + (lane - 1)] = pair_dist_d(qq, ca[idx]);
            int i1 = __shfl(idx, 1, 64);
            int i2 = __shfl(idx, 2, 64);
            int i3 = __shfl(idx, 3, 64);
            if (lane < 3) {
                int pa = (lane == 2) ? i2 : i1;
                int pb = (lane == 0) ? i2 : i3;
                intra_after[s * 6 + 3 + lane] = pair_dist_d(ca[pa], ca[pb]);
            }
        }
    }
}

// ---------------------------------------------------------------- fused tail (cooperative)
struct PhA {
    float sW1[28 * 128];
    float sb1[128];
    int s_ni[4][16];
    float s_rf[4][448];
    float s_ia[4][8];
    float s_adf[16][28];
};
struct PhB { float l1[256]; float l2[256]; float sc, sh; };
struct PhC { float sW[92 * 128]; float t2[16 * 129]; float scat[16 * 92]; };
union TailU { PhA a; PhB b; PhC c; };

__global__ __launch_bounds__(256) void fused_tail_kernel(
        const float4* __restrict__ ca, const float4* __restrict__ cb,
        const int* __restrict__ ni_i, const float* __restrict__ intra_after,
        const int* __restrict__ a_before, const float* __restrict__ intra_before,
        const int* __restrict__ sidx,
        const float* __restrict__ Ww, const float* __restrict__ bw,
        const float* __restrict__ Wb, const float* __restrict__ bb,
        const float* __restrict__ gw, const float* __restrict__ betaw,
        const float* __restrict__ gb, const float* __restrict__ betab,
        const float* __restrict__ feature,
        const float* __restrict__ Wo, const float* __restrict__ bo,
        const float* __restrict__ go, const float* __restrict__ betao,
        float* __restrict__ out_rf, float* __restrict__ adf,
        float* __restrict__ y_wb, float* __restrict__ scale1,
        float* __restrict__ shift1, float* __restrict__ y_o,
        float* __restrict__ out_feat) {
    cg::grid_group grid = cg::this_grid();
    __shared__ TailU su;
    int t = threadIdx.x, wid = t >> 6, lane = t & 63;
    int b = blockIdx.x;

    // ---- Phase A: assemble + mlp1 (16 samples/block) ----
    for (int i = t; i < 28 * 128; i += 256) {
        int k = i >> 7, c = i & 127;
        su.a.sW1[i] = (c < 64) ? Ww[k * 64 + c] : Wb[k * 64 + (c - 64)];
    }
    if (t < 128) su.a.sb1[t] = (t < 64) ? bw[t] : bb[t - 64];
    __syncthreads();
    for (int r = 0; r < 4; ++r) {
        int s = b * 16 + r * 4 + wid;
        int slot = r * 4 + wid;
        if (lane < 16) su.a.s_ni[wid][lane] = ni_i[s * 16 + lane];
        if (lane < 6) su.a.s_ia[wid][lane] = intra_after[s * 6 + lane];
        __syncthreads();
        int k = lane >> 2, qq = lane & 3;
        int nai_q = ni_i[su.a.s_ni[wid][k] * 16 + qq];
        float4 pq = ca[nai_q];
#pragma unroll
        for (int p = 0; p < 4; ++p) {
            float4 pp = ca[su.a.s_ni[wid][p]];
            su.a.s_rf[wid][k * 28 + 12 + p * 4 + qq] = pair_dist_d(pp, pq);
        }
        for (int idx = lane; idx < 16 * 12; idx += 64) {
            int kk = idx / 12, c = idx % 12;
            float v = (c < 6) ? su.a.s_ia[wid][c]
                              : intra_after[su.a.s_ni[wid][kk] * 6 + (c - 6)];
            su.a.s_rf[wid][kk * 28 + c] = v;
        }
        if (lane < 16) {
            int p = lane >> 2, q2 = lane & 3;
            int ib = a_before[s * 4 + p];
            int ia = sidx[su.a.s_ni[wid][q2]];
            float v = pair_dist_d(cb[ib], cb[ia]);
            adf[s * 28 + 12 + lane] = v;
            su.a.s_adf[slot][12 + lane] = v;
        } else if (lane >= 32 && lane < 38) {
            float v = intra_before[s * 6 + (lane - 32)];
            adf[s * 28 + (lane - 32)] = v;
            su.a.s_adf[slot][lane - 32] = v;
        } else if (lane >= 40 && lane < 46) {
            float v = su.a.s_ia[wid][lane - 40];
            adf[s * 28 + 6 + (lane - 40)] = v;
            su.a.s_adf[slot][6 + (lane - 40)] = v;
        }
        const int base = s * 16 * 28;
        for (int idx = lane; idx < 16 * 28; idx += 64)
            out_rf[base + idx] = su.a.s_rf[wid][idx];
        __syncthreads();
    }
    // mlp1 for the block's 16 samples
    int sbase = b * 16;
    for (int o = t; o < 2048; o += 256) {
        int r2 = o >> 7, c = o & 127;
        float acc = su.a.sb1[c];
#pragma unroll
        for (int k2 = 0; k2 < 28; ++k2)
            acc = fmaf(su.a.s_adf[r2][k2], su.a.sW1[k2 * 128 + c], acc);
        y_wb[c * 4096 + sbase + r2] = acc;
    }
    grid.sync();

    // ---- Phase B: batchnorm stats for y_wb (blocks 0..127) ----
    if (b < 128) {
        int c = b;
        const float* p = y_wb + c * 4096;
        float s1 = 0.0f, s2 = 0.0f;
        for (int i = t; i < 4096; i += 256) {
            float v = p[i];
            s1 += v;
            s2 = fmaf(v, v, s2);
        }
        su.b.l1[t] = s1;
        su.b.l2[t] = s2;
        __syncthreads();
        for (int off = 128; off; off >>= 1) {
            if (t < off) { su.b.l1[t] += su.b.l1[t + off]; su.b.l2[t] += su.b.l2[t + off]; }
            __syncthreads();
        }
        if (t == 0) {
            float mean = su.b.l1[0] * (1.0f / 4096.0f);
            float var = su.b.l2[0] * (1.0f / 4096.0f) - mean * mean;
            float g = (c < 64) ? gw[c] : gb[c - 64];
            float be = (c < 64) ? betaw[c] : betab[c - 64];
            float sc = g / sqrtf(var + 1e-5f);
            scale1[c] = sc;
            shift1[c] = be - mean * sc;
        }
    }
    grid.sync();

    // ---- Phase C: mlp2 (16 samples/block) ----
    {
        int s0 = b * 16;
        for (int i = t; i < 92 * 128; i += 256) su.c.sW[i] = Wo[i];
        for (int i = t; i < 16 * 128; i += 256) {
            int row = i & 15, c = i >> 4;
            su.c.t2[row * 129 + c] =
                fmaf(y_wb[c * 4096 + s0 + row], scale1[c], shift1[c]);
        }
        __syncthreads();
        for (int rr = 0; rr < 16; rr += 4) {
            int r = rr + (t >> 6);
            int c = t & 63;
            int si = sidx[s0 + r];
            float f = feature[si * 64 + c];
            float v = fmaf(f, su.c.t2[r * 129 + c], su.c.t2[r * 129 + 64 + c]);
            su.c.scat[r * 92 + c] = v >= 0.0f ? v : 0.2f * v;
        }
        for (int i = t; i < 16 * 28; i += 256) {
            int row = i / 28, k = i % 28;
            su.c.scat[row * 92 + 64 + k] = adf[(s0 + row) * 28 + k];
        }
        __syncthreads();
        int r = t >> 4, cg2 = t & 15;
        float acc[8];
#pragma unroll
        for (int j = 0; j < 8; ++j) acc[j] = bo[cg2 * 8 + j];
        for (int c = 0; c < 92; ++c) {
            float a = su.c.scat[r * 92 + c];
#pragma unroll
            for (int j = 0; j < 8; ++j)
                acc[j] = fmaf(a, su.c.sW[c * 128 + cg2 * 8 + j], acc[j]);
        }
        int s = s0 + r;
#pragma unroll
        for (int j = 0; j < 8; ++j) y_o[(cg2 * 8 + j) * 4096 + s] = acc[j];
    }
    grid.sync();

    // ---- Phase D: stats + normalize + lrelu for y_o (blocks 0..127) ----
    if (b < 128) {
        int j = b;
        const float* p = y_o + j * 4096;
        float s1 = 0.0f, s2 = 0.0f;
        for (int i = t; i < 4096; i += 256) {
            float v = p[i];
            s1 += v;
            s2 = fmaf(v, v, s2);
        }
        su.b.l1[t] = s1;
        su.b.l2[t] = s2;
        __syncthreads();
        for (int off = 128; off; off >>= 1) {
            if (t < off) { su.b.l1[t] += su.b.l1[t + off]; su.b.l2[t] += su.b.l2[t + off]; }
            __syncthreads();
        }
        if (t == 0) {
            float mean = su.b.l1[0] * (1.0f / 4096.0f);
            float var = su.b.l2[0] * (1.0f / 4096.0f) - mean * mean;
            float sc = go[j] / sqrtf(var + 1e-5f);
            su.b.sc = sc;
            su.b.sh = betao[j] - mean * sc;
        }
        __syncthreads();
        float sc = su.b.sc, sh = su.b.sh;
        for (int i = t; i < 4096; i += 256) {
            float v = fmaf(p[i], sc, sh);
            v = v >= 0.0f ? v : 0.2f * v;
            out_feat[i * 128 + j] = v;
        }
    }
}

// ----------------------------------------------------------------
extern "C" void kernel_launch(void* const* d_in, const int* in_sizes, int n_in,
                              void* d_out, int out_size, void* d_ws, size_t ws_size,
                              hipStream_t stream) {
    const float* xyz = (const float*)d_in[0];
    const float* feature = (const float*)d_in[1];
    const int* sidx = (const int*)d_in[2];
    const float* Ww = (const float*)d_in[3];
    const float* bw = (const float*)d_in[4];
    const float* gw = (const float*)d_in[5];
    const float* betaw = (const float*)d_in[6];
    const float* Wb = (const float*)d_in[7];
    const float* bb = (const float*)d_in[8];
    const float* gb = (const float*)d_in[9];
    const float* betab = (const float*)d_in[10];
    const float* Wo = (const float*)d_in[11];
    const float* bo = (const float*)d_in[12];
    const float* go = (const float*)d_in[13];
    const float* betao = (const float*)d_in[14];

    float* out = (float*)d_out;
    float* out_xyz = out;                                  // 4096*3
    float* out_feat = out + 12288;                         // 4096*128
    float* out_rf = out + 12288 + 524288;                  // 4096*16*28
    float* out_ni = out + 12288 + 524288 + 1835008;        // 4096*16

    float* ws = (float*)d_ws;
    float4* cb = (float4*)ws;                  // 8192 float4
    float4* ca = (float4*)(ws + 32768);        // 4096 float4
    int* a_before = (int*)(ws + 49152);        // 4096*4
    float* intra_before = ws + 65536;          // 4096*6
    int* ni_i = (int*)(ws + 90112);            // 4096*16
    float* intra_after = ws + 155648;          // 4096*6
    float* adf = ws + 180224;                  // 4096*28
    float* y_wb = ws + 294912;                 // 128*4096
    float* y_o = ws + 819200;                  // 128*4096
    float* scale1 = ws + 1343488;              // 128
    float* shift1 = ws + 1343616;              // 128
    int* inv = (int*)(ws + 1343744);           // 8192 ints

    hipMemsetAsync(inv, 0xFF, N_PTS * sizeof(int), stream);
    stage_kernel<<<32, 256, 0, stream>>>(xyz, sidx, cb, ca, inv, out_xyz);
    knn_kernel<<<512, 256, 0, stream>>>(cb, ca, inv, sidx, a_before, intra_before,
                                        ni_i, intra_after, out_ni);
    {
        const float4* ca_ = ca; const float4* cb_ = cb;
        const int* ni_ = ni_i; const float* ia_ = intra_after;
        const int* ab_ = a_before; const float* ib_ = intra_before;
        const int* sx_ = sidx;
        void* args[] = {
            (void*)&ca_, (void*)&cb_, (void*)&ni_, (void*)&ia_,
            (void*)&ab_, (void*)&ib_, (void*)&sx_,
            (void*)&Ww, (void*)&bw, (void*)&Wb, (void*)&bb,
            (void*)&gw, (void*)&betaw, (void*)&gb, (void*)&betab,
            (void*)&feature, (void*)&Wo, (void*)&bo, (void*)&go, (void*)&betao,
            (void*)&out_rf, (void*)&adf, (void*)&y_wb, (void*)&scale1,
            (void*)&shift1, (void*)&y_o, (void*)&out_feat };
        hipLaunchCooperativeKernel((const void*)fused_tail_kernel, dim3(256),
                                   dim3(256), args, 0, stream);
    }
}

// Round 12
// 189.605 us; speedup vs baseline: 1.7593x; 1.7593x over previous
//
#include <hip/hip_runtime.h>
#include <hip/hip_bf16.h>
#include <math.h>

#define N_PTS 8192
#define S_PTS 4096
#define CAP 128
typedef unsigned long long u64;
typedef unsigned u32;

// Double-precision pair distance, rounded to float (accurate output values).
__device__ __forceinline__ float pair_dist_d(const float4 a, const float4 b) {
    double ax = a.x, ay = a.y, az = a.z;
    double bx = b.x, by = b.y, bz = b.z;
    double dx = ax - bx, dy = ay - by, dz = az - bz;
    double d2 = dx * dx + dy * dy + dz * dz;
    return d2 > 0.0 ? (float)sqrt(d2) : 0.0f;
}

// Strict fp32 gram-formula d^2 (bit-identical to the reference cdist pipeline).
__device__ __forceinline__ float d2_f32_gram(const float4 a, const float4 b) {
    float dot = __fadd_rn(__fadd_rn(__fmul_rn(a.x, b.x), __fmul_rn(a.y, b.y)),
                          __fmul_rn(a.z, b.z));
    float d2 = __fsub_rn(__fadd_rn(a.w, b.w), __fmul_rn(2.0f, dot));
    return fmaxf(d2, 0.0f);
}

__device__ __forceinline__ u32 bitonic64_u32(u32 v, int lane) {
#pragma unroll
    for (int k = 2; k <= 64; k <<= 1) {
#pragma unroll
        for (int j2 = k >> 1; j2 >= 1; j2 >>= 1) {
            u32 o = __shfl_xor(v, j2, 64);
            bool keepMin = (((lane & j2) == 0) == ((lane & k) == 0));
            bool less = o < v;
            v = keepMin ? (less ? o : v) : (less ? v : o);
        }
    }
    return v;
}

__device__ __forceinline__ u64 bitonic64_u64(u64 v, int lane) {
#pragma unroll
    for (int k = 2; k <= 64; k <<= 1) {
#pragma unroll
        for (int j2 = k >> 1; j2 >= 1; j2 >>= 1) {
            u64 o = __shfl_xor(v, j2, 64);
            bool keepMin = (((lane & j2) == 0) == ((lane & k) == 0));
            bool less = o < v;
            v = keepMin ? (less ? o : v) : (less ? v : o);
        }
    }
    return v;
}

// ---------------------------------------------------------------- stage
__global__ __launch_bounds__(256) void stage_kernel(
        const float* __restrict__ xyz, const int* __restrict__ sidx,
        float4* __restrict__ cb, float4* __restrict__ ca,
        int* __restrict__ inv, float* __restrict__ out_xyz_s) {
    int i = blockIdx.x * blockDim.x + threadIdx.x;
    if (i < N_PTS) {
        float x = xyz[i * 3 + 0], y = xyz[i * 3 + 1], z = xyz[i * 3 + 2];
        float sq = __fadd_rn(__fadd_rn(__fmul_rn(x, x), __fmul_rn(y, y)),
                             __fmul_rn(z, z));
        cb[i] = make_float4(x, y, z, sq);
    }
    if (i < S_PTS) {
        int si = sidx[i];
        float x = xyz[si * 3 + 0], y = xyz[si * 3 + 1], z = xyz[si * 3 + 2];
        float sq = __fadd_rn(__fadd_rn(__fmul_rn(x, x), __fmul_rn(y, y)),
                             __fmul_rn(z, z));
        ca[i] = make_float4(x, y, z, sq);
        inv[si] = i;  // inv pre-set to -1 by hipMemsetAsync(0xFF)
        out_xyz_s[i * 3 + 0] = x;
        out_xyz_s[i * 3 + 1] = y;
        out_xyz_s[i * 3 + 2] = z;
    }
}

// ---------------------------------------------------------------- knn fallbacks
template <int K, bool AFTER>
__device__ u64 cold_ladder(const float4 q, const float4* __restrict__ cb,
                           const int* __restrict__ inv, int lane) {
    u64 L[K];
#pragma unroll
    for (int j = 0; j < K; ++j) L[j] = ~0ull;
    for (int c = lane; c < N_PTS; c += 64) {
        int low = c;
        bool ok = true;
        if (AFTER) { int iv = inv[c]; ok = iv >= 0; low = iv; }
        if (!ok) continue;
        float d2 = d2_f32_gram(q, cb[c]);
        float D = d2 > 0.0f ? __fsqrt_rn(d2) : 0.0f;
        u64 key = ((u64)__float_as_uint(D) << 32) | (u64)(u32)low;
        if (key < L[K - 1]) {
#pragma unroll
            for (int j = K - 1; j >= 1; --j)
                L[j] = (key < L[j - 1]) ? L[j - 1] : ((key < L[j]) ? key : L[j]);
            L[0] = (key < L[0]) ? key : L[0];
        }
    }
    u64 res = ~0ull;
#pragma unroll
    for (int r = 0; r < K; ++r) {
        u64 m = L[0];
#pragma unroll
        for (int off = 32; off >= 1; off >>= 1) {
            u64 o = __shfl_xor(m, off, 64);
            m = (o < m) ? o : m;
        }
        if (lane == r) res = m;
        if (L[0] == m) {
#pragma unroll
            for (int j = 0; j < K - 1; ++j) L[j] = L[j + 1];
            L[K - 1] = ~0ull;
        }
    }
    return res;
}

// sort collected candidates (cnt <= CAP), lane r gets rank r
template <int K>
__device__ u64 finalize_sort(const u64* buf, u32 cnt, int lane) {
    if (cnt <= 64u) {
        u64 v = (lane < (int)cnt) ? buf[lane] : ~0ull;
        return bitonic64_u64(v, lane);
    }
    u64 L0 = ~0ull, L1 = ~0ull, L2 = ~0ull, L3 = ~0ull;
    for (u32 mm = lane; mm < cnt; mm += 64) {
        u64 kk = buf[mm];
        if (kk < L3) {
            if (kk < L1) {
                L3 = L2; L2 = L1;
                if (kk < L0) { L1 = L0; L0 = kk; } else L1 = kk;
            } else {
                if (kk < L2) { L3 = L2; L2 = kk; } else L3 = kk;
            }
        }
    }
    u64 res = ~0ull;
#pragma unroll
    for (int r = 0; r < K; ++r) {
        u64 mr = L0;
#pragma unroll
        for (int off = 32; off >= 1; off >>= 1) {
            u64 o = __shfl_xor(mr, off, 64);
            mr = (o < mr) ? o : mr;
        }
        if (lane == r) res = mr;
        if (L0 == mr) { L0 = L1; L1 = L2; L2 = L3; L3 = ~0ull; }
    }
    return res;
}

// ---------------------------------------------------------------- knn: 8 queries/block, recompute pass 2, no tiling
// Streams: st in [0,8) = before (K=4, all cb, key low = cb idx);
//          st in [8,16) = after (K=16, sampled only, key low = inv[c]).
// tau per stream = K-th smallest of 64 folded per-thread minima: the K lanes
// with smallest folded minima each contribute a distinct candidate <= tau,
// so collecting d2 <= tau yields >= K (exact superset; final order exact).
__global__ __launch_bounds__(256) void knn_kernel(
        const float4* __restrict__ cb, const float4* __restrict__ ca,
        const int* __restrict__ inv, const int* __restrict__ sidx,
        int* __restrict__ a_before, float* __restrict__ intra_before,
        int* __restrict__ ni_i, float* __restrict__ intra_after,
        float* __restrict__ out_ni) {
    __shared__ u32 smin[16][256];   // 16 KB
    __shared__ u64 sbuf[16][CAP];   // 16 KB
    __shared__ u32 staus[16];
    __shared__ u32 scnt[16];
    __shared__ float4 sq[8];
    int t = threadIdx.x, lane = t & 63, wid = t >> 6;
    int s0 = blockIdx.x * 8;
    if (t < 8) sq[t] = cb[sidx[s0 + t]];
    if (t < 16) scnt[t] = 0;
    __syncthreads();
    float4 q[8];
#pragma unroll
    for (int i = 0; i < 8; ++i) q[i] = sq[i];

    // pass 1: running minima (16 regs)
    u32 mB[8], mA[8];
#pragma unroll
    for (int i = 0; i < 8; ++i) { mB[i] = ~0u; mA[i] = ~0u; }
    for (int c = t; c < N_PTS; c += 256) {
        float4 p = cb[c];
        bool smp = inv[c] >= 0;
#pragma unroll
        for (int i = 0; i < 8; ++i) {
            u32 b = __float_as_uint(d2_f32_gram(q[i], p));
            mB[i] = b < mB[i] ? b : mB[i];
            if (smp) mA[i] = b < mA[i] ? b : mA[i];
        }
    }
#pragma unroll
    for (int i = 0; i < 8; ++i) { smin[i][t] = mB[i]; smin[8 + i][t] = mA[i]; }
    __syncthreads();
    // taus: wave w handles streams w*4 .. w*4+3
#pragma unroll
    for (int m = 0; m < 4; ++m) {
        int st = wid * 4 + m;
        u32 v = smin[st][lane];
        u32 v2 = smin[st][lane + 64];  v = v2 < v ? v2 : v;
        v2 = smin[st][lane + 128];     v = v2 < v ? v2 : v;
        v2 = smin[st][lane + 192];     v = v2 < v ? v2 : v;
        v = bitonic64_u32(v, lane);
        int kk = (st < 8) ? 3 : 15;
        if (lane == kk) staus[st] = v;
    }
    __syncthreads();
    u32 tB[8], tA[8];
#pragma unroll
    for (int i = 0; i < 8; ++i) { tB[i] = staus[i]; tA[i] = staus[8 + i]; }

    // pass 2: recompute + sparse collection (~0.5% qualify)
    for (int c = t; c < N_PTS; c += 256) {
        float4 p = cb[c];
        int iv = inv[c];
        bool smp = iv >= 0;
#pragma unroll
        for (int i = 0; i < 8; ++i) {
            u32 b = __float_as_uint(d2_f32_gram(q[i], p));
            bool qb = b <= tB[i];
            bool qa = smp && (b <= tA[i]);
            if (qb || qa) {
                float d2v = __uint_as_float(b);
                float D = d2v > 0.0f ? __fsqrt_rn(d2v) : 0.0f;
                u64 hk = (u64)__float_as_uint(D) << 32;
                if (qb) {
                    u32 pos = atomicAdd(&scnt[i], 1u);
                    if (pos < CAP) sbuf[i][pos] = hk | (u64)(u32)c;
                }
                if (qa) {
                    u32 pos = atomicAdd(&scnt[8 + i], 1u);
                    if (pos < CAP) sbuf[8 + i][pos] = hk | (u64)(u32)iv;
                }
            }
        }
    }
    __syncthreads();
    // sorts + outputs: wave w handles streams w*4 .. w*4+3 (uniform kind/wave)
#pragma unroll
    for (int m = 0; m < 4; ++m) {
        int st = wid * 4 + m;
        u32 cnt = scnt[st];
        if (st < 8) {
            int s = s0 + st;
            float4 qq = q[st];
            u64 res = (cnt <= CAP) ? finalize_sort<4>(sbuf[st], cnt, lane)
                                   : cold_ladder<4, false>(qq, cb, inv, lane);
            int idx = (int)(res & 0xffffffffull);
            if (lane < 4) a_before[s * 4 + lane] = idx;
            if (lane >= 1 && lane < 4)
                intra_before[s * 6 + (lane - 1)] = pair_dist_d(qq, cb[idx]);
            int i1 = __shfl(idx, 1, 64);
            int i2 = __shfl(idx, 2, 64);
            int i3 = __shfl(idx, 3, 64);
            if (lane < 3) {  // pairs (1,2),(1,3),(2,3)
                int pa = (lane == 2) ? i2 : i1;
                int pb = (lane == 0) ? i2 : i3;
                intra_before[s * 6 + 3 + lane] = pair_dist_d(cb[pa], cb[pb]);
            }
        } else {
            int s = s0 + (st - 8);
            float4 qq = q[st - 8];
            u64 res = (cnt <= CAP) ? finalize_sort<16>(sbuf[st], cnt, lane)
                                   : cold_ladder<16, true>(qq, cb, inv, lane);
            int idx = (int)(res & 0xffffffffull);
            if (lane < 16) {
                ni_i[s * 16 + lane] = idx;
                out_ni[s * 16 + lane] = (float)idx;
            }
            if (lane >= 1 && lane < 4)
                intra_after[s * 6 + (lane - 1)] = pair_dist_d(qq, ca[idx]);
            int i1 = __shfl(idx, 1, 64);
            int i2 = __shfl(idx, 2, 64);
            int i3 = __shfl(idx, 3, 64);
            if (lane < 3) {
                int pa = (lane == 2) ? i2 : i1;
                int pb = (lane == 0) ? i2 : i3;
                intra_after[s * 6 + 3 + lane] = pair_dist_d(ca[pa], ca[pb]);
            }
        }
    }
}

// ---------------------------------------------------------------- rf_after assembly + adf (4 samples/block)
__global__ __launch_bounds__(256) void assemble_kernel(
        const float4* __restrict__ ca, const float4* __restrict__ cb,
        const int* __restrict__ ni_i, const float* __restrict__ intra_after,
        const int* __restrict__ a_before, const float* __restrict__ intra_before,
        const int* __restrict__ sidx,
        float* __restrict__ out_rf, float* __restrict__ adf) {
    __shared__ int s_ni[4][16];
    __shared__ float s_rf[4][16 * 28];
    __shared__ float s_ia[4][8];
    int t = threadIdx.x, wid = t >> 6, lane = t & 63;
    int s = blockIdx.x * 4 + wid;
    if (lane < 16) s_ni[wid][lane] = ni_i[s * 16 + lane];
    if (lane < 6) s_ia[wid][lane] = intra_after[s * 6 + lane];
    __syncthreads();

    int k = lane >> 2, qq = lane & 3;
    int nai_q = ni_i[s_ni[wid][k] * 16 + qq];
    float4 pq = ca[nai_q];
#pragma unroll
    for (int p = 0; p < 4; ++p) {
        float4 pp = ca[s_ni[wid][p]];
        s_rf[wid][k * 28 + 12 + p * 4 + qq] = pair_dist_d(pp, pq);
    }
    for (int idx = lane; idx < 16 * 12; idx += 64) {
        int kk = idx / 12, c = idx % 12;
        float v = (c < 6) ? s_ia[wid][c] : intra_after[s_ni[wid][kk] * 6 + (c - 6)];
        s_rf[wid][kk * 28 + c] = v;
    }
    if (lane < 16) {
        int p = lane >> 2, q2 = lane & 3;
        int ib = a_before[s * 4 + p];
        int ia = sidx[s_ni[wid][q2]];
        adf[s * 28 + 12 + lane] = pair_dist_d(cb[ib], cb[ia]);
    } else if (lane >= 32 && lane < 38) {
        adf[s * 28 + (lane - 32)] = intra_before[s * 6 + (lane - 32)];
    } else if (lane >= 40 && lane < 46) {
        adf[s * 28 + 6 + (lane - 40)] = s_ia[wid][lane - 40];
    }
    __syncthreads();
    const int base = s * 16 * 28;
    for (int idx = lane; idx < 16 * 28; idx += 64) out_rf[base + idx] = s_rf[wid][idx];
}

// ---------------------------------------------------------------- mlp1 (32 samples/block, 128 blocks)
__global__ __launch_bounds__(256) void mlp1_kernel(
        const float* __restrict__ adf,
        const float* __restrict__ Ww, const float* __restrict__ bw,
        const float* __restrict__ Wb, const float* __restrict__ bb,
        float* __restrict__ y_wb) {
    __shared__ float sW[28 * 128];
    __shared__ float sb[128];
    __shared__ float sA[32 * 28];
    int t = threadIdx.x;
    for (int i = t; i < 28 * 128; i += 256) {
        int k = i >> 7, c = i & 127;
        sW[i] = (c < 64) ? Ww[k * 64 + c] : Wb[k * 64 + (c - 64)];
    }
    if (t < 128) sb[t] = (t < 64) ? bw[t] : bb[t - 64];
    int s0 = blockIdx.x * 32;
    for (int i = t; i < 32 * 28; i += 256) sA[i] = adf[s0 * 28 + i];
    __syncthreads();
    int sl = t >> 3, grp = t & 7;
    int s = s0 + sl;
    float acc[16];
#pragma unroll
    for (int k = 0; k < 16; ++k) acc[k] = sb[grp * 16 + k];
    for (int k2 = 0; k2 < 28; ++k2) {
        float a = sA[sl * 28 + k2];
#pragma unroll
        for (int k = 0; k < 16; ++k)
            acc[k] = fmaf(a, sW[k2 * 128 + grp * 16 + k], acc[k]);
    }
#pragma unroll
    for (int k = 0; k < 16; ++k) y_wb[(grp * 16 + k) * 4096 + s] = acc[k];
}

// ---------------------------------------------------------------- batchnorm stats: block per channel
__global__ __launch_bounds__(256) void stats_kernel(
        const float* __restrict__ y,  // [C][4096]
        const float* __restrict__ g0, const float* __restrict__ be0,
        const float* __restrict__ g1, const float* __restrict__ be1, int csplit,
        float* __restrict__ scale, float* __restrict__ shift) {
    int c = blockIdx.x;
    const float* p = y + c * 4096;
    float s1 = 0.0f, s2 = 0.0f;
    for (int i = threadIdx.x; i < 4096; i += 256) {
        float v = p[i];
        s1 += v;
        s2 = fmaf(v, v, s2);
    }
    __shared__ float l1[256], l2[256];
    l1[threadIdx.x] = s1;
    l2[threadIdx.x] = s2;
    __syncthreads();
    for (int off = 128; off; off >>= 1) {
        if (threadIdx.x < off) {
            l1[threadIdx.x] += l1[threadIdx.x + off];
            l2[threadIdx.x] += l2[threadIdx.x + off];
        }
        __syncthreads();
    }
    if (threadIdx.x == 0) {
        float mean = l1[0] * (1.0f / 4096.0f);
        float var = l2[0] * (1.0f / 4096.0f) - mean * mean;
        float g = (c < csplit) ? g0[c] : g1[c - csplit];
        float be = (c < csplit) ? be0[c] : be1[c - csplit];
        float sc = g / sqrtf(var + 1e-5f);
        scale[c] = sc;
        shift[c] = be - mean * sc;
    }
}

// ---------------------------------------------------------------- mlp2
__global__ __launch_bounds__(256) void mlp2_kernel(
        const float* __restrict__ y_wb,
        const float* __restrict__ scale1, const float* __restrict__ shift1,
        const float* __restrict__ feature, const int* __restrict__ sidx,
        const float* __restrict__ adf,
        const float* __restrict__ Wo, const float* __restrict__ bo,
        float* __restrict__ y_o) {
    __shared__ float sW[92 * 128];
    __shared__ float t2[16 * 129];
    __shared__ float scat[16 * 92];
    int t = threadIdx.x;
    int s0 = blockIdx.x * 16;
    for (int i = t; i < 92 * 128; i += 256) sW[i] = Wo[i];
    for (int i = t; i < 16 * 128; i += 256) {
        int row = i & 15, c = i >> 4;
        t2[row * 129 + c] = fmaf(y_wb[c * 4096 + s0 + row], scale1[c], shift1[c]);
    }
    __syncthreads();
    for (int rr = 0; rr < 16; rr += 4) {
        int r = rr + (t >> 6);
        int c = t & 63;
        int si = sidx[s0 + r];
        float f = feature[si * 64 + c];
        float v = fmaf(f, t2[r * 129 + c], t2[r * 129 + 64 + c]);
        scat[r * 92 + c] = v >= 0.0f ? v : 0.2f * v;
    }
    for (int i = t; i < 16 * 28; i += 256) {
        int row = i / 28, k = i % 28;
        scat[row * 92 + 64 + k] = adf[(s0 + row) * 28 + k];
    }
    __syncthreads();
    int r = t >> 4, cg = t & 15;
    float acc[8];
#pragma unroll
    for (int j = 0; j < 8; ++j) acc[j] = bo[cg * 8 + j];
    for (int c = 0; c < 92; ++c) {
        float a = scat[r * 92 + c];
#pragma unroll
        for (int j = 0; j < 8; ++j)
            acc[j] = fmaf(a, sW[c * 128 + cg * 8 + j], acc[j]);
    }
    int s = s0 + r;
#pragma unroll
    for (int j = 0; j < 8; ++j) y_o[(cg * 8 + j) * 4096 + s] = acc[j];
}

// ---------------------------------------------------------------- final: normalize + lrelu, write feat
__global__ __launch_bounds__(256) void final_kernel(
        const float* __restrict__ y_o,
        const float* __restrict__ scale, const float* __restrict__ shift,
        float* __restrict__ out_feat) {
    int tid = blockIdx.x * 256 + threadIdx.x;  // 0..524287
    int j = tid >> 12;
    int s = tid & 4095;
    float v = fmaf(y_o[tid], scale[j], shift[j]);
    v = v >= 0.0f ? v : 0.2f * v;
    out_feat[s * 128 + j] = v;
}

// ----------------------------------------------------------------
extern "C" void kernel_launch(void* const* d_in, const int* in_sizes, int n_in,
                              void* d_out, int out_size, void* d_ws, size_t ws_size,
                              hipStream_t stream) {
    const float* xyz = (const float*)d_in[0];
    const float* feature = (const float*)d_in[1];
    const int* sidx = (const int*)d_in[2];
    const float* Ww = (const float*)d_in[3];
    const float* bw = (const float*)d_in[4];
    const float* gw = (const float*)d_in[5];
    const float* betaw = (const float*)d_in[6];
    const float* Wb = (const float*)d_in[7];
    const float* bb = (const float*)d_in[8];
    const float* gb = (const float*)d_in[9];
    const float* betab = (const float*)d_in[10];
    const float* Wo = (const float*)d_in[11];
    const float* bo = (const float*)d_in[12];
    const float* go = (const float*)d_in[13];
    const float* betao = (const float*)d_in[14];

    float* out = (float*)d_out;
    float* out_xyz = out;                                  // 4096*3
    float* out_feat = out + 12288;                         // 4096*128
    float* out_rf = out + 12288 + 524288;                  // 4096*16*28
    float* out_ni = out + 12288 + 524288 + 1835008;        // 4096*16

    float* ws = (float*)d_ws;
    float4* cb = (float4*)ws;                  // 8192 float4
    float4* ca = (float4*)(ws + 32768);        // 4096 float4
    int* a_before = (int*)(ws + 49152);        // 4096*4
    float* intra_before = ws + 65536;          // 4096*6
    int* ni_i = (int*)(ws + 90112);            // 4096*16
    float* intra_after = ws + 155648;          // 4096*6
    float* adf = ws + 180224;                  // 4096*28
    float* y_wb = ws + 294912;                 // 128*4096
    float* y_o = ws + 819200;                  // 128*4096
    float* scale1 = ws + 1343488;              // 128
    float* shift1 = ws + 1343616;              // 128
    float* scale_o = ws + 1343744;             // 128
    float* shift_o = ws + 1343872;             // 128
    int* inv = (int*)(ws + 1344000);           // 8192 ints

    hipMemsetAsync(inv, 0xFF, N_PTS * sizeof(int), stream);
    stage_kernel<<<32, 256, 0, stream>>>(xyz, sidx, cb, ca, inv, out_xyz);
    knn_kernel<<<512, 256, 0, stream>>>(cb, ca, inv, sidx, a_before, intra_before,
                                        ni_i, intra_after, out_ni);
    assemble_kernel<<<1024, 256, 0, stream>>>(ca, cb, ni_i, intra_after, a_before,
                                              intra_before, sidx, out_rf, adf);
    mlp1_kernel<<<128, 256, 0, stream>>>(adf, Ww, bw, Wb, bb, y_wb);
    stats_kernel<<<128, 256, 0, stream>>>(y_wb, gw, betaw, gb, betab, 64, scale1, shift1);
    mlp2_kernel<<<256, 256, 0, stream>>>(y_wb, scale1, shift1, feature, sidx, adf, Wo, bo, y_o);
    stats_kernel<<<128, 256, 0, stream>>>(y_o, go, betao, go, betao, 128, scale_o, shift_o);
    final_kernel<<<2048, 256, 0, stream>>>(y_o, scale_o, shift_o, out_feat);
}

// Round 13
// 182.778 us; speedup vs baseline: 1.8250x; 1.0373x over previous
//
#include <hip/hip_runtime.h>
#include <hip/hip_bf16.h>
#include <math.h>

#define N_PTS 8192
#define S_PTS 4096
#define CAP 256
typedef unsigned long long u64;
typedef unsigned u32;

// Double-precision pair distance, rounded to float (accurate output values).
__device__ __forceinline__ float pair_dist_d(const float4 a, const float4 b) {
    double ax = a.x, ay = a.y, az = a.z;
    double bx = b.x, by = b.y, bz = b.z;
    double dx = ax - bx, dy = ay - by, dz = az - bz;
    double d2 = dx * dx + dy * dy + dz * dz;
    return d2 > 0.0 ? (float)sqrt(d2) : 0.0f;
}

// Strict fp32 gram-formula d^2 (bit-identical to the reference cdist pipeline).
__device__ __forceinline__ float d2_f32_gram(const float4 a, const float4 b) {
    float dot = __fadd_rn(__fadd_rn(__fmul_rn(a.x, b.x), __fmul_rn(a.y, b.y)),
                          __fmul_rn(a.z, b.z));
    float d2 = __fsub_rn(__fadd_rn(a.w, b.w), __fmul_rn(2.0f, dot));
    return fmaxf(d2, 0.0f);
}

__device__ __forceinline__ u32 bitonic64_u32(u32 v, int lane) {
#pragma unroll
    for (int k = 2; k <= 64; k <<= 1) {
#pragma unroll
        for (int j2 = k >> 1; j2 >= 1; j2 >>= 1) {
            u32 o = __shfl_xor(v, j2, 64);
            bool keepMin = (((lane & j2) == 0) == ((lane & k) == 0));
            bool less = o < v;
            v = keepMin ? (less ? o : v) : (less ? v : o);
        }
    }
    return v;
}

__device__ __forceinline__ u64 bitonic64_u64(u64 v, int lane) {
#pragma unroll
    for (int k = 2; k <= 64; k <<= 1) {
#pragma unroll
        for (int j2 = k >> 1; j2 >= 1; j2 >>= 1) {
            u64 o = __shfl_xor(v, j2, 64);
            bool keepMin = (((lane & j2) == 0) == ((lane & k) == 0));
            bool less = o < v;
            v = keepMin ? (less ? o : v) : (less ? v : o);
        }
    }
    return v;
}

// ---------------------------------------------------------------- stage
__global__ __launch_bounds__(256) void stage_kernel(
        const float* __restrict__ xyz, const int* __restrict__ sidx,
        float4* __restrict__ cb, float4* __restrict__ ca,
        float* __restrict__ out_xyz_s) {
    int i = blockIdx.x * blockDim.x + threadIdx.x;
    if (i < N_PTS) {
        float x = xyz[i * 3 + 0], y = xyz[i * 3 + 1], z = xyz[i * 3 + 2];
        float sq = __fadd_rn(__fadd_rn(__fmul_rn(x, x), __fmul_rn(y, y)),
                             __fmul_rn(z, z));
        cb[i] = make_float4(x, y, z, sq);
    }
    if (i < S_PTS) {
        int si = sidx[i];
        float x = xyz[si * 3 + 0], y = xyz[si * 3 + 1], z = xyz[si * 3 + 2];
        float sq = __fadd_rn(__fadd_rn(__fmul_rn(x, x), __fmul_rn(y, y)),
                             __fmul_rn(z, z));
        ca[i] = make_float4(x, y, z, sq);
        out_xyz_s[i * 3 + 0] = x;
        out_xyz_s[i * 3 + 1] = y;
        out_xyz_s[i * 3 + 2] = z;
    }
}

// ---------------------------------------------------------------- knn helpers
// Spill-free exact fallback: K rounds of "wave-min over keys > prev".
// Only runs if collection overflowed CAP (expected never for this data).
template <int K>
__device__ u64 rescan_topk(const float4 q, const float4* __restrict__ pts,
                           int n, int lane) {
    u64 res = ~0ull;
    u64 prev = 0;
    for (int r = 0; r < K; ++r) {
        u64 best = ~0ull;
        for (int c = lane; c < n; c += 64) {
            float d2 = d2_f32_gram(q, pts[c]);
            float D = d2 > 0.0f ? __fsqrt_rn(d2) : 0.0f;
            u64 key = ((u64)__float_as_uint(D) << 32) | (u64)(u32)c;
            bool ok = (r == 0) || (key > prev);
            if (ok && key < best) best = key;
        }
#pragma unroll
        for (int off = 32; off >= 1; off >>= 1) {
            u64 o = __shfl_xor(best, off, 64);
            best = (o < best) ? o : best;
        }
        if (lane == r) res = best;
        prev = best;
    }
    return res;
}

// sort collected candidates (cnt <= CAP), lane r gets rank r
template <int K>
__device__ u64 finalize_sort(const u64* buf, u32 cnt, int lane) {
    if (cnt <= 64u) {
        u64 v = (lane < (int)cnt) ? buf[lane] : ~0ull;
        return bitonic64_u64(v, lane);
    }
    u64 L0 = ~0ull, L1 = ~0ull, L2 = ~0ull, L3 = ~0ull;
    for (u32 mm = lane; mm < cnt; mm += 64) {
        u64 kk = buf[mm];
        if (kk < L3) {
            if (kk < L1) {
                L3 = L2; L2 = L1;
                if (kk < L0) { L1 = L0; L0 = kk; } else L1 = kk;
            } else {
                if (kk < L2) { L3 = L2; L2 = kk; } else L3 = kk;
            }
        }
    }
    u64 res = ~0ull;
#pragma unroll
    for (int r = 0; r < K; ++r) {
        u64 mr = L0;
#pragma unroll
        for (int off = 32; off >= 1; off >>= 1) {
            u64 o = __shfl_xor(mr, off, 64);
            mr = (o < mr) ? o : mr;
        }
        if (lane == r) res = mr;
        if (L0 == mr) { L0 = L1; L1 = L2; L2 = L3; L3 = ~0ull; }
    }
    return res;
}

// ---------------------------------------------------------------- knn: 4 queries/block, 1024 blocks
// before-streams (0..3): top-4 over cb (8192); after-streams (4..7): top-16
// over ca (4096, key low = ca idx — same tie semantics as ref, self D==0).
// tau per stream = K-th smallest of 64 folded per-thread minima (valid upper
// bound on the true K-th smallest); collect d2 <= tau (>= K guaranteed),
// exact (fp32-gram D, idx) sort.
__global__ __launch_bounds__(256) void knn_kernel(
        const float4* __restrict__ cb, const float4* __restrict__ ca,
        const int* __restrict__ sidx,
        int* __restrict__ a_before, float* __restrict__ intra_before,
        int* __restrict__ ni_i, float* __restrict__ intra_after,
        float* __restrict__ out_ni) {
    __shared__ u32 smin[8][256];   // 8 KB
    __shared__ u64 sbuf[8][CAP];   // 16 KB
    __shared__ u32 staus[8];
    __shared__ u32 scnt[8];
    __shared__ float4 sq[4];
    int t = threadIdx.x, lane = t & 63, wid = t >> 6;
    int s0 = blockIdx.x * 4;
    if (t < 4) sq[t] = cb[sidx[s0 + t]];
    if (t < 8) scnt[t] = 0;
    __syncthreads();
    float4 q[4];
#pragma unroll
    for (int i = 0; i < 4; ++i) q[i] = sq[i];

    // pass 1: running minima
    u32 mB[4], mA[4];
#pragma unroll
    for (int i = 0; i < 4; ++i) { mB[i] = ~0u; mA[i] = ~0u; }
    for (int c = t; c < N_PTS; c += 256) {
        float4 p = cb[c];
#pragma unroll
        for (int i = 0; i < 4; ++i) {
            u32 b = __float_as_uint(d2_f32_gram(q[i], p));
            mB[i] = b < mB[i] ? b : mB[i];
        }
    }
    for (int c = t; c < S_PTS; c += 256) {
        float4 p = ca[c];
#pragma unroll
        for (int i = 0; i < 4; ++i) {
            u32 b = __float_as_uint(d2_f32_gram(q[i], p));
            mA[i] = b < mA[i] ? b : mA[i];
        }
    }
#pragma unroll
    for (int i = 0; i < 4; ++i) { smin[i][t] = mB[i]; smin[4 + i][t] = mA[i]; }
    __syncthreads();
    // taus: wave w folds+sorts streams w (K=4) and 4+w (K=16)
#pragma unroll
    for (int m = 0; m < 2; ++m) {
        int st = (m == 0) ? wid : wid + 4;
        u32 v = smin[st][lane];
        u32 v2 = smin[st][lane + 64];  v = v2 < v ? v2 : v;
        v2 = smin[st][lane + 128];     v = v2 < v ? v2 : v;
        v2 = smin[st][lane + 192];     v = v2 < v ? v2 : v;
        v = bitonic64_u32(v, lane);
        int kk = (st < 4) ? 3 : 15;
        if (lane == kk) staus[st] = v;
    }
    __syncthreads();
    u32 tB[4], tA[4];
#pragma unroll
    for (int i = 0; i < 4; ++i) { tB[i] = staus[i]; tA[i] = staus[4 + i]; }

    // pass 2: recompute + sparse collection
    for (int c = t; c < N_PTS; c += 256) {
        float4 p = cb[c];
#pragma unroll
        for (int i = 0; i < 4; ++i) {
            u32 b = __float_as_uint(d2_f32_gram(q[i], p));
            if (b <= tB[i]) {
                float d2v = __uint_as_float(b);
                float D = d2v > 0.0f ? __fsqrt_rn(d2v) : 0.0f;
                u32 pos = atomicAdd(&scnt[i], 1u);
                if (pos < CAP)
                    sbuf[i][pos] = ((u64)__float_as_uint(D) << 32) | (u64)(u32)c;
            }
        }
    }
    for (int c = t; c < S_PTS; c += 256) {
        float4 p = ca[c];
#pragma unroll
        for (int i = 0; i < 4; ++i) {
            u32 b = __float_as_uint(d2_f32_gram(q[i], p));
            if (b <= tA[i]) {
                float d2v = __uint_as_float(b);
                float D = d2v > 0.0f ? __fsqrt_rn(d2v) : 0.0f;
                u32 pos = atomicAdd(&scnt[4 + i], 1u);
                if (pos < CAP)
                    sbuf[4 + i][pos] = ((u64)__float_as_uint(D) << 32) | (u64)(u32)c;
            }
        }
    }
    __syncthreads();
    // wave w: query w's before (K=4) and after (K=16) outputs
    {
        int s = s0 + wid;
        float4 qq = q[wid];
        u32 cnt = scnt[wid];
        u64 res = (cnt <= CAP) ? finalize_sort<4>(sbuf[wid], cnt, lane)
                               : rescan_topk<4>(qq, cb, N_PTS, lane);
        int idx = (int)(res & 0xffffffffull);
        if (lane < 4) a_before[s * 4 + lane] = idx;
        if (lane >= 1 && lane < 4)
            intra_before[s * 6 + (lane - 1)] = pair_dist_d(qq, cb[idx]);
        int i1 = __shfl(idx, 1, 64);
        int i2 = __shfl(idx, 2, 64);
        int i3 = __shfl(idx, 3, 64);
        if (lane < 3) {  // pairs (1,2),(1,3),(2,3)
            int pa = (lane == 2) ? i2 : i1;
            int pb = (lane == 0) ? i2 : i3;
            intra_before[s * 6 + 3 + lane] = pair_dist_d(cb[pa], cb[pb]);
        }
        cnt = scnt[4 + wid];
        res = (cnt <= CAP) ? finalize_sort<16>(sbuf[4 + wid], cnt, lane)
                           : rescan_topk<16>(qq, ca, S_PTS, lane);
        idx = (int)(res & 0xffffffffull);
        if (lane < 16) {
            ni_i[s * 16 + lane] = idx;
            out_ni[s * 16 + lane] = (float)idx;
        }
        if (lane >= 1 && lane < 4)
            intra_after[s * 6 + (lane - 1)] = pair_dist_d(qq, ca[idx]);
        i1 = __shfl(idx, 1, 64);
        i2 = __shfl(idx, 2, 64);
        i3 = __shfl(idx, 3, 64);
        if (lane < 3) {
            int pa = (lane == 2) ? i2 : i1;
            int pb = (lane == 0) ? i2 : i3;
            intra_after[s * 6 + 3 + lane] = pair_dist_d(ca[pa], ca[pb]);
        }
    }
}

// ---------------------------------------------------------------- rf_after assembly + adf (4 samples/block)
__global__ __launch_bounds__(256) void assemble_kernel(
        const float4* __restrict__ ca, const float4* __restrict__ cb,
        const int* __restrict__ ni_i, const float* __restrict__ intra_after,
        const int* __restrict__ a_before, const float* __restrict__ intra_before,
        const int* __restrict__ sidx,
        float* __restrict__ out_rf, float* __restrict__ adf) {
    __shared__ int s_ni[4][16];
    __shared__ float s_rf[4][16 * 28];
    __shared__ float s_ia[4][8];
    int t = threadIdx.x, wid = t >> 6, lane = t & 63;
    int s = blockIdx.x * 4 + wid;
    if (lane < 16) s_ni[wid][lane] = ni_i[s * 16 + lane];
    if (lane < 6) s_ia[wid][lane] = intra_after[s * 6 + lane];
    __syncthreads();

    int k = lane >> 2, qq = lane & 3;
    int nai_q = ni_i[s_ni[wid][k] * 16 + qq];
    float4 pq = ca[nai_q];
#pragma unroll
    for (int p = 0; p < 4; ++p) {
        float4 pp = ca[s_ni[wid][p]];
        s_rf[wid][k * 28 + 12 + p * 4 + qq] = pair_dist_d(pp, pq);
    }
    for (int idx = lane; idx < 16 * 12; idx += 64) {
        int kk = idx / 12, c = idx % 12;
        float v = (c < 6) ? s_ia[wid][c] : intra_after[s_ni[wid][kk] * 6 + (c - 6)];
        s_rf[wid][kk * 28 + c] = v;
    }
    if (lane < 16) {
        int p = lane >> 2, q2 = lane & 3;
        int ib = a_before[s * 4 + p];
        int ia = sidx[s_ni[wid][q2]];
        adf[s * 28 + 12 + lane] = pair_dist_d(cb[ib], cb[ia]);
    } else if (lane >= 32 && lane < 38) {
        adf[s * 28 + (lane - 32)] = intra_before[s * 6 + (lane - 32)];
    } else if (lane >= 40 && lane < 46) {
        adf[s * 28 + 6 + (lane - 40)] = s_ia[wid][lane - 40];
    }
    __syncthreads();
    const int base = s * 16 * 28;
    for (int idx = lane; idx < 16 * 28; idx += 64) out_rf[base + idx] = s_rf[wid][idx];
}

// ---------------------------------------------------------------- mlp1 (16 samples/block, 256 blocks, float4 weights)
__global__ __launch_bounds__(256) void mlp1_kernel(
        const float* __restrict__ adf,
        const float* __restrict__ Ww, const float* __restrict__ bw,
        const float* __restrict__ Wb, const float* __restrict__ bb,
        float* __restrict__ y_wb) {
    __shared__ float sW[28 * 128];
    __shared__ float sb[128];
    __shared__ float sA[16 * 28];
    int t = threadIdx.x;
    for (int i = t; i < 28 * 128; i += 256) {
        int k = i >> 7, c = i & 127;
        sW[i] = (c < 64) ? Ww[k * 64 + c] : Wb[k * 64 + (c - 64)];
    }
    if (t < 128) sb[t] = (t < 64) ? bw[t] : bb[t - 64];
    int s0 = blockIdx.x * 16;
    for (int i = t; i < 16 * 28; i += 256) sA[i] = adf[s0 * 28 + i];
    __syncthreads();
    int sl = t >> 4, grp = t & 15;
    int s = s0 + sl;
    float acc[8];
#pragma unroll
    for (int k = 0; k < 8; ++k) acc[k] = sb[grp * 8 + k];
    for (int k2 = 0; k2 < 28; ++k2) {
        float a = sA[sl * 28 + k2];
        float4 w0 = *(const float4*)&sW[k2 * 128 + grp * 8];
        float4 w1 = *(const float4*)&sW[k2 * 128 + grp * 8 + 4];
        acc[0] = fmaf(a, w0.x, acc[0]);
        acc[1] = fmaf(a, w0.y, acc[1]);
        acc[2] = fmaf(a, w0.z, acc[2]);
        acc[3] = fmaf(a, w0.w, acc[3]);
        acc[4] = fmaf(a, w1.x, acc[4]);
        acc[5] = fmaf(a, w1.y, acc[5]);
        acc[6] = fmaf(a, w1.z, acc[6]);
        acc[7] = fmaf(a, w1.w, acc[7]);
    }
#pragma unroll
    for (int k = 0; k < 8; ++k) y_wb[(grp * 8 + k) * 4096 + s] = acc[k];
}

// ---------------------------------------------------------------- batchnorm stats: block per channel
__global__ __launch_bounds__(256) void stats_kernel(
        const float* __restrict__ y,  // [C][4096]
        const float* __restrict__ g0, const float* __restrict__ be0,
        const float* __restrict__ g1, const float* __restrict__ be1, int csplit,
        float* __restrict__ scale, float* __restrict__ shift) {
    int c = blockIdx.x;
    const float* p = y + c * 4096;
    float s1 = 0.0f, s2 = 0.0f;
    for (int i = threadIdx.x; i < 4096; i += 256) {
        float v = p[i];
        s1 += v;
        s2 = fmaf(v, v, s2);
    }
    __shared__ float l1[256], l2[256];
    l1[threadIdx.x] = s1;
    l2[threadIdx.x] = s2;
    __syncthreads();
    for (int off = 128; off; off >>= 1) {
        if (threadIdx.x < off) {
            l1[threadIdx.x] += l1[threadIdx.x + off];
            l2[threadIdx.x] += l2[threadIdx.x + off];
        }
        __syncthreads();
    }
    if (threadIdx.x == 0) {
        float mean = l1[0] * (1.0f / 4096.0f);
        float var = l2[0] * (1.0f / 4096.0f) - mean * mean;
        float g = (c < csplit) ? g0[c] : g1[c - csplit];
        float be = (c < csplit) ? be0[c] : be1[c - csplit];
        float sc = g / sqrtf(var + 1e-5f);
        scale[c] = sc;
        shift[c] = be - mean * sc;
    }
}

// ---------------------------------------------------------------- mlp2 (float4 weight reads)
__global__ __launch_bounds__(256) void mlp2_kernel(
        const float* __restrict__ y_wb,
        const float* __restrict__ scale1, const float* __restrict__ shift1,
        const float* __restrict__ feature, const int* __restrict__ sidx,
        const float* __restrict__ adf,
        const float* __restrict__ Wo, const float* __restrict__ bo,
        float* __restrict__ y_o) {
    __shared__ float sW[92 * 128];
    __shared__ float t2[16 * 129];
    __shared__ float scat[16 * 92];
    int t = threadIdx.x;
    int s0 = blockIdx.x * 16;
    for (int i = t; i < 92 * 128; i += 256) sW[i] = Wo[i];
    for (int i = t; i < 16 * 128; i += 256) {
        int row = i & 15, c = i >> 4;
        t2[row * 129 + c] = fmaf(y_wb[c * 4096 + s0 + row], scale1[c], shift1[c]);
    }
    __syncthreads();
    for (int rr = 0; rr < 16; rr += 4) {
        int r = rr + (t >> 6);
        int c = t & 63;
        int si = sidx[s0 + r];
        float f = feature[si * 64 + c];
        float v = fmaf(f, t2[r * 129 + c], t2[r * 129 + 64 + c]);
        scat[r * 92 + c] = v >= 0.0f ? v : 0.2f * v;
    }
    for (int i = t; i < 16 * 28; i += 256) {
        int row = i / 28, k = i % 28;
        scat[row * 92 + 64 + k] = adf[(s0 + row) * 28 + k];
    }
    __syncthreads();
    int r = t >> 4, cg = t & 15;
    float acc[8];
#pragma unroll
    for (int j = 0; j < 8; ++j) acc[j] = bo[cg * 8 + j];
    for (int c = 0; c < 92; ++c) {
        float a = scat[r * 92 + c];
        float4 w0 = *(const float4*)&sW[c * 128 + cg * 8];
        float4 w1 = *(const float4*)&sW[c * 128 + cg * 8 + 4];
        acc[0] = fmaf(a, w0.x, acc[0]);
        acc[1] = fmaf(a, w0.y, acc[1]);
        acc[2] = fmaf(a, w0.z, acc[2]);
        acc[3] = fmaf(a, w0.w, acc[3]);
        acc[4] = fmaf(a, w1.x, acc[4]);
        acc[5] = fmaf(a, w1.y, acc[5]);
        acc[6] = fmaf(a, w1.z, acc[6]);
        acc[7] = fmaf(a, w1.w, acc[7]);
    }
    int s = s0 + r;
#pragma unroll
    for (int j = 0; j < 8; ++j) y_o[(cg * 8 + j) * 4096 + s] = acc[j];
}

// ---------------------------------------------------------------- final: normalize + lrelu, write feat
__global__ __launch_bounds__(256) void final_kernel(
        const float* __restrict__ y_o,
        const float* __restrict__ scale, const float* __restrict__ shift,
        float* __restrict__ out_feat) {
    int tid = blockIdx.x * 256 + threadIdx.x;  // 0..524287
    int j = tid >> 12;
    int s = tid & 4095;
    float v = fmaf(y_o[tid], scale[j], shift[j]);
    v = v >= 0.0f ? v : 0.2f * v;
    out_feat[s * 128 + j] = v;
}

// ----------------------------------------------------------------
extern "C" void kernel_launch(void* const* d_in, const int* in_sizes, int n_in,
                              void* d_out, int out_size, void* d_ws, size_t ws_size,
                              hipStream_t stream) {
    const float* xyz = (const float*)d_in[0];
    const float* feature = (const float*)d_in[1];
    const int* sidx = (const int*)d_in[2];
    const float* Ww = (const float*)d_in[3];
    const float* bw = (const float*)d_in[4];
    const float* gw = (const float*)d_in[5];
    const float* betaw = (const float*)d_in[6];
    const float* Wb = (const float*)d_in[7];
    const float* bb = (const float*)d_in[8];
    const float* gb = (const float*)d_in[9];
    const float* betab = (const float*)d_in[10];
    const float* Wo = (const float*)d_in[11];
    const float* bo = (const float*)d_in[12];
    const float* go = (const float*)d_in[13];
    const float* betao = (const float*)d_in[14];

    float* out = (float*)d_out;
    float* out_xyz = out;                                  // 4096*3
    float* out_feat = out + 12288;                         // 4096*128
    float* out_rf = out + 12288 + 524288;                  // 4096*16*28
    float* out_ni = out + 12288 + 524288 + 1835008;        // 4096*16

    float* ws = (float*)d_ws;
    float4* cb = (float4*)ws;                  // 8192 float4
    float4* ca = (float4*)(ws + 32768);        // 4096 float4
    int* a_before = (int*)(ws + 49152);        // 4096*4
    float* intra_before = ws + 65536;          // 4096*6
    int* ni_i = (int*)(ws + 90112);            // 4096*16
    float* intra_after = ws + 155648;          // 4096*6
    float* adf = ws + 180224;                  // 4096*28
    float* y_wb = ws + 294912;                 // 128*4096
    float* y_o = ws + 819200;                  // 128*4096
    float* scale1 = ws + 1343488;              // 128
    float* shift1 = ws + 1343616;              // 128
    float* scale_o = ws + 1343744;             // 128
    float* shift_o = ws + 1343872;             // 128

    stage_kernel<<<32, 256, 0, stream>>>(xyz, sidx, cb, ca, out_xyz);
    knn_kernel<<<1024, 256, 0, stream>>>(cb, ca, sidx, a_before, intra_before,
                                         ni_i, intra_after, out_ni);
    assemble_kernel<<<1024, 256, 0, stream>>>(ca, cb, ni_i, intra_after, a_before,
                                              intra_before, sidx, out_rf, adf);
    mlp1_kernel<<<256, 256, 0, stream>>>(adf, Ww, bw, Wb, bb, y_wb);
    stats_kernel<<<128, 256, 0, stream>>>(y_wb, gw, betaw, gb, betab, 64, scale1, shift1);
    mlp2_kernel<<<256, 256, 0, stream>>>(y_wb, scale1, shift1, feature, sidx, adf, Wo, bo, y_o);
    stats_kernel<<<128, 256, 0, stream>>>(y_o, go, betao, go, betao, 128, scale_o, shift_o);
    final_kernel<<<2048, 256, 0, stream>>>(y_o, scale_o, shift_o, out_feat);
}

// Round 14
// 181.918 us; speedup vs baseline: 1.8336x; 1.0047x over previous
//
#include <hip/hip_runtime.h>
#include <hip/hip_bf16.h>
#include <math.h>

#define N_PTS 8192
#define S_PTS 4096
#define CAP 256
typedef unsigned long long u64;
typedef unsigned u32;

// Double-precision pair distance, rounded to float (accurate output values).
__device__ __forceinline__ float pair_dist_d(const float4 a, const float4 b) {
    double ax = a.x, ay = a.y, az = a.z;
    double bx = b.x, by = b.y, bz = b.z;
    double dx = ax - bx, dy = ay - by, dz = az - bz;
    double d2 = dx * dx + dy * dy + dz * dz;
    return d2 > 0.0 ? (float)sqrt(d2) : 0.0f;
}

// Strict fp32 gram-formula d^2 (bit-identical to the reference cdist pipeline).
__device__ __forceinline__ float d2_f32_gram(const float4 a, const float4 b) {
    float dot = __fadd_rn(__fadd_rn(__fmul_rn(a.x, b.x), __fmul_rn(a.y, b.y)),
                          __fmul_rn(a.z, b.z));
    float d2 = __fsub_rn(__fadd_rn(a.w, b.w), __fmul_rn(2.0f, dot));
    return fmaxf(d2, 0.0f);
}

__device__ __forceinline__ u32 bitonic64_u32(u32 v, int lane) {
#pragma unroll
    for (int k = 2; k <= 64; k <<= 1) {
#pragma unroll
        for (int j2 = k >> 1; j2 >= 1; j2 >>= 1) {
            u32 o = __shfl_xor(v, j2, 64);
            bool keepMin = (((lane & j2) == 0) == ((lane & k) == 0));
            bool less = o < v;
            v = keepMin ? (less ? o : v) : (less ? v : o);
        }
    }
    return v;
}

__device__ __forceinline__ u64 bitonic64_u64(u64 v, int lane) {
#pragma unroll
    for (int k = 2; k <= 64; k <<= 1) {
#pragma unroll
        for (int j2 = k >> 1; j2 >= 1; j2 >>= 1) {
            u64 o = __shfl_xor(v, j2, 64);
            bool keepMin = (((lane & j2) == 0) == ((lane & k) == 0));
            bool less = o < v;
            v = keepMin ? (less ? o : v) : (less ? v : o);
        }
    }
    return v;
}

// ---------------------------------------------------------------- stage
__global__ __launch_bounds__(256) void stage_kernel(
        const float* __restrict__ xyz, const int* __restrict__ sidx,
        float4* __restrict__ cb, float4* __restrict__ ca,
        float* __restrict__ out_xyz_s) {
    int i = blockIdx.x * blockDim.x + threadIdx.x;
    if (i < N_PTS) {
        float x = xyz[i * 3 + 0], y = xyz[i * 3 + 1], z = xyz[i * 3 + 2];
        float sq = __fadd_rn(__fadd_rn(__fmul_rn(x, x), __fmul_rn(y, y)),
                             __fmul_rn(z, z));
        cb[i] = make_float4(x, y, z, sq);
    }
    if (i < S_PTS) {
        int si = sidx[i];
        float x = xyz[si * 3 + 0], y = xyz[si * 3 + 1], z = xyz[si * 3 + 2];
        float sq = __fadd_rn(__fadd_rn(__fmul_rn(x, x), __fmul_rn(y, y)),
                             __fmul_rn(z, z));
        ca[i] = make_float4(x, y, z, sq);
        out_xyz_s[i * 3 + 0] = x;
        out_xyz_s[i * 3 + 1] = y;
        out_xyz_s[i * 3 + 2] = z;
    }
}

// ---------------------------------------------------------------- knn helpers
// Spill-free exact fallback: K rounds of "wave-min over keys > prev".
template <int K>
__device__ u64 rescan_topk(const float4 q, const float4* __restrict__ pts,
                           int n, int lane) {
    u64 res = ~0ull;
    u64 prev = 0;
    for (int r = 0; r < K; ++r) {
        u64 best = ~0ull;
        for (int c = lane; c < n; c += 64) {
            float d2 = d2_f32_gram(q, pts[c]);
            float D = d2 > 0.0f ? __fsqrt_rn(d2) : 0.0f;
            u64 key = ((u64)__float_as_uint(D) << 32) | (u64)(u32)c;
            bool ok = (r == 0) || (key > prev);
            if (ok && key < best) best = key;
        }
#pragma unroll
        for (int off = 32; off >= 1; off >>= 1) {
            u64 o = __shfl_xor(best, off, 64);
            best = (o < best) ? o : best;
        }
        if (lane == r) res = best;
        prev = best;
    }
    return res;
}

// sort collected candidates (cnt <= CAP), lane r gets rank r
template <int K>
__device__ u64 finalize_sort(const u64* buf, u32 cnt, int lane) {
    if (cnt <= 64u) {
        u64 v = (lane < (int)cnt) ? buf[lane] : ~0ull;
        return bitonic64_u64(v, lane);
    }
    u64 L0 = ~0ull, L1 = ~0ull, L2 = ~0ull, L3 = ~0ull;
    for (u32 mm = lane; mm < cnt; mm += 64) {
        u64 kk = buf[mm];
        if (kk < L3) {
            if (kk < L1) {
                L3 = L2; L2 = L1;
                if (kk < L0) { L1 = L0; L0 = kk; } else L1 = kk;
            } else {
                if (kk < L2) { L3 = L2; L2 = kk; } else L3 = kk;
            }
        }
    }
    u64 res = ~0ull;
#pragma unroll
    for (int r = 0; r < K; ++r) {
        u64 mr = L0;
#pragma unroll
        for (int off = 32; off >= 1; off >>= 1) {
            u64 o = __shfl_xor(mr, off, 64);
            mr = (o < mr) ? o : mr;
        }
        if (lane == r) res = mr;
        if (L0 == mr) { L0 = L1; L1 = L2; L2 = L3; L3 = ~0ull; }
    }
    return res;
}

// ---------------------------------------------------------------- knn: 4 queries/block, unroll-4 candidate loop
__global__ __launch_bounds__(256) void knn_kernel(
        const float4* __restrict__ cb, const float4* __restrict__ ca,
        const int* __restrict__ sidx,
        int* __restrict__ a_before, float* __restrict__ intra_before,
        int* __restrict__ ni_i, float* __restrict__ intra_after,
        float* __restrict__ out_ni) {
    __shared__ u32 smin[8][256];   // 8 KB
    __shared__ u64 sbuf[8][CAP];   // 16 KB
    __shared__ u32 staus[8];
    __shared__ u32 scnt[8];
    __shared__ float4 sq[4];
    int t = threadIdx.x, lane = t & 63, wid = t >> 6;
    int s0 = blockIdx.x * 4;
    if (t < 4) sq[t] = cb[sidx[s0 + t]];
    if (t < 8) scnt[t] = 0;
    __syncthreads();
    float4 q[4];
#pragma unroll
    for (int i = 0; i < 4; ++i) q[i] = sq[i];

    // pass 1: running minima, 4 loads in flight
    u32 mB[4], mA[4];
#pragma unroll
    for (int i = 0; i < 4; ++i) { mB[i] = ~0u; mA[i] = ~0u; }
    for (int c = t; c < N_PTS; c += 1024) {
        float4 p0 = cb[c];
        float4 p1 = cb[c + 256];
        float4 p2 = cb[c + 512];
        float4 p3 = cb[c + 768];
#pragma unroll
        for (int i = 0; i < 4; ++i) {
            u32 b0 = __float_as_uint(d2_f32_gram(q[i], p0));
            u32 b1 = __float_as_uint(d2_f32_gram(q[i], p1));
            u32 b2 = __float_as_uint(d2_f32_gram(q[i], p2));
            u32 b3 = __float_as_uint(d2_f32_gram(q[i], p3));
            u32 m01 = b0 < b1 ? b0 : b1;
            u32 m23 = b2 < b3 ? b2 : b3;
            u32 m = m01 < m23 ? m01 : m23;
            mB[i] = m < mB[i] ? m : mB[i];
        }
    }
    for (int c = t; c < S_PTS; c += 1024) {
        float4 p0 = ca[c];
        float4 p1 = ca[c + 256];
        float4 p2 = ca[c + 512];
        float4 p3 = ca[c + 768];
#pragma unroll
        for (int i = 0; i < 4; ++i) {
            u32 b0 = __float_as_uint(d2_f32_gram(q[i], p0));
            u32 b1 = __float_as_uint(d2_f32_gram(q[i], p1));
            u32 b2 = __float_as_uint(d2_f32_gram(q[i], p2));
            u32 b3 = __float_as_uint(d2_f32_gram(q[i], p3));
            u32 m01 = b0 < b1 ? b0 : b1;
            u32 m23 = b2 < b3 ? b2 : b3;
            u32 m = m01 < m23 ? m01 : m23;
            mA[i] = m < mA[i] ? m : mA[i];
        }
    }
#pragma unroll
    for (int i = 0; i < 4; ++i) { smin[i][t] = mB[i]; smin[4 + i][t] = mA[i]; }
    __syncthreads();
    // taus: wave w folds+sorts streams w (K=4) and 4+w (K=16)
#pragma unroll
    for (int m = 0; m < 2; ++m) {
        int st = (m == 0) ? wid : wid + 4;
        u32 v = smin[st][lane];
        u32 v2 = smin[st][lane + 64];  v = v2 < v ? v2 : v;
        v2 = smin[st][lane + 128];     v = v2 < v ? v2 : v;
        v2 = smin[st][lane + 192];     v = v2 < v ? v2 : v;
        v = bitonic64_u32(v, lane);
        int kk = (st < 4) ? 3 : 15;
        if (lane == kk) staus[st] = v;
    }
    __syncthreads();
    u32 tB[4], tA[4];
#pragma unroll
    for (int i = 0; i < 4; ++i) { tB[i] = staus[i]; tA[i] = staus[4 + i]; }

    // pass 2: recompute + sparse collection, 4 loads in flight
    for (int c = t; c < N_PTS; c += 1024) {
        float4 p0 = cb[c];
        float4 p1 = cb[c + 256];
        float4 p2 = cb[c + 512];
        float4 p3 = cb[c + 768];
#pragma unroll
        for (int i = 0; i < 4; ++i) {
            u32 b0 = __float_as_uint(d2_f32_gram(q[i], p0));
            u32 b1 = __float_as_uint(d2_f32_gram(q[i], p1));
            u32 b2 = __float_as_uint(d2_f32_gram(q[i], p2));
            u32 b3 = __float_as_uint(d2_f32_gram(q[i], p3));
            if (b0 <= tB[i] || b1 <= tB[i] || b2 <= tB[i] || b3 <= tB[i]) {
#pragma unroll
                for (int u = 0; u < 4; ++u) {
                    u32 b = (u == 0) ? b0 : (u == 1) ? b1 : (u == 2) ? b2 : b3;
                    if (b <= tB[i]) {
                        float d2v = __uint_as_float(b);
                        float D = d2v > 0.0f ? __fsqrt_rn(d2v) : 0.0f;
                        u32 pos = atomicAdd(&scnt[i], 1u);
                        if (pos < CAP)
                            sbuf[i][pos] = ((u64)__float_as_uint(D) << 32) |
                                           (u64)(u32)(c + 256 * u);
                    }
                }
            }
        }
    }
    for (int c = t; c < S_PTS; c += 1024) {
        float4 p0 = ca[c];
        float4 p1 = ca[c + 256];
        float4 p2 = ca[c + 512];
        float4 p3 = ca[c + 768];
#pragma unroll
        for (int i = 0; i < 4; ++i) {
            u32 b0 = __float_as_uint(d2_f32_gram(q[i], p0));
            u32 b1 = __float_as_uint(d2_f32_gram(q[i], p1));
            u32 b2 = __float_as_uint(d2_f32_gram(q[i], p2));
            u32 b3 = __float_as_uint(d2_f32_gram(q[i], p3));
            if (b0 <= tA[i] || b1 <= tA[i] || b2 <= tA[i] || b3 <= tA[i]) {
#pragma unroll
                for (int u = 0; u < 4; ++u) {
                    u32 b = (u == 0) ? b0 : (u == 1) ? b1 : (u == 2) ? b2 : b3;
                    if (b <= tA[i]) {
                        float d2v = __uint_as_float(b);
                        float D = d2v > 0.0f ? __fsqrt_rn(d2v) : 0.0f;
                        u32 pos = atomicAdd(&scnt[4 + i], 1u);
                        if (pos < CAP)
                            sbuf[4 + i][pos] = ((u64)__float_as_uint(D) << 32) |
                                               (u64)(u32)(c + 256 * u);
                    }
                }
            }
        }
    }
    __syncthreads();
    // wave w: query w's before (K=4) and after (K=16) outputs
    {
        int s = s0 + wid;
        float4 qq = q[wid];
        u32 cnt = scnt[wid];
        u64 res = (cnt <= CAP) ? finalize_sort<4>(sbuf[wid], cnt, lane)
                               : rescan_topk<4>(qq, cb, N_PTS, lane);
        int idx = (int)(res & 0xffffffffull);
        if (lane < 4) a_before[s * 4 + lane] = idx;
        if (lane >= 1 && lane < 4)
            intra_before[s * 6 + (lane - 1)] = pair_dist_d(qq, cb[idx]);
        int i1 = __shfl(idx, 1, 64);
        int i2 = __shfl(idx, 2, 64);
        int i3 = __shfl(idx, 3, 64);
        if (lane < 3) {  // pairs (1,2),(1,3),(2,3)
            int pa = (lane == 2) ? i2 : i1;
            int pb = (lane == 0) ? i2 : i3;
            intra_before[s * 6 + 3 + lane] = pair_dist_d(cb[pa], cb[pb]);
        }
        cnt = scnt[4 + wid];
        res = (cnt <= CAP) ? finalize_sort<16>(sbuf[4 + wid], cnt, lane)
                           : rescan_topk<16>(qq, ca, S_PTS, lane);
        idx = (int)(res & 0xffffffffull);
        if (lane < 16) {
            ni_i[s * 16 + lane] = idx;
            out_ni[s * 16 + lane] = (float)idx;
        }
        if (lane >= 1 && lane < 4)
            intra_after[s * 6 + (lane - 1)] = pair_dist_d(qq, ca[idx]);
        i1 = __shfl(idx, 1, 64);
        i2 = __shfl(idx, 2, 64);
        i3 = __shfl(idx, 3, 64);
        if (lane < 3) {
            int pa = (lane == 2) ? i2 : i1;
            int pb = (lane == 0) ? i2 : i3;
            intra_after[s * 6 + 3 + lane] = pair_dist_d(ca[pa], ca[pb]);
        }
    }
}

// ---------------------------------------------------------------- assemble + mlp1 fused (validated in R10)
// 4 samples per block (one wave each); then 28->128 linear for those samples.
__global__ __launch_bounds__(256) void asm_mlp1_kernel(
        const float4* __restrict__ ca, const float4* __restrict__ cb,
        const int* __restrict__ ni_i, const float* __restrict__ intra_after,
        const int* __restrict__ a_before, const float* __restrict__ intra_before,
        const int* __restrict__ sidx,
        const float* __restrict__ Ww, const float* __restrict__ bw,
        const float* __restrict__ Wb, const float* __restrict__ bb,
        float* __restrict__ out_rf, float* __restrict__ adf,
        float* __restrict__ y_wb) {
    __shared__ int s_ni[4][16];
    __shared__ float s_rf[4][448];
    __shared__ float s_ia[4][8];
    __shared__ float s_adf[4][28];
    __shared__ float sW[28 * 128];   // col c<64: Ww, else Wb
    __shared__ float sb[128];
    int t = threadIdx.x, wid = t >> 6, lane = t & 63;
    int s = blockIdx.x * 4 + wid;
    for (int i = t; i < 28 * 128; i += 256) {
        int k = i >> 7, c = i & 127;
        sW[i] = (c < 64) ? Ww[k * 64 + c] : Wb[k * 64 + (c - 64)];
    }
    if (t < 128) sb[t] = (t < 64) ? bw[t] : bb[t - 64];
    if (lane < 16) s_ni[wid][lane] = ni_i[s * 16 + lane];
    if (lane < 6) s_ia[wid][lane] = intra_after[s * 6 + lane];
    __syncthreads();

    int k = lane >> 2, qq = lane & 3;
    int nai_q = ni_i[s_ni[wid][k] * 16 + qq];
    float4 pq = ca[nai_q];
#pragma unroll
    for (int p = 0; p < 4; ++p) {
        float4 pp = ca[s_ni[wid][p]];
        s_rf[wid][k * 28 + 12 + p * 4 + qq] = pair_dist_d(pp, pq);
    }
    for (int idx = lane; idx < 16 * 12; idx += 64) {
        int kk = idx / 12, c = idx % 12;
        float v = (c < 6) ? s_ia[wid][c] : intra_after[s_ni[wid][kk] * 6 + (c - 6)];
        s_rf[wid][kk * 28 + c] = v;
    }
    if (lane < 16) {
        int p = lane >> 2, q2 = lane & 3;
        int ib = a_before[s * 4 + p];
        int ia = sidx[s_ni[wid][q2]];
        float v = pair_dist_d(cb[ib], cb[ia]);
        adf[s * 28 + 12 + lane] = v;
        s_adf[wid][12 + lane] = v;
    } else if (lane >= 32 && lane < 38) {
        float v = intra_before[s * 6 + (lane - 32)];
        adf[s * 28 + (lane - 32)] = v;
        s_adf[wid][lane - 32] = v;
    } else if (lane >= 40 && lane < 46) {
        float v = s_ia[wid][lane - 40];
        adf[s * 28 + 6 + (lane - 40)] = v;
        s_adf[wid][6 + (lane - 40)] = v;
    }
    const int base = s * 16 * 28;
    for (int idx = lane; idx < 16 * 28; idx += 64) out_rf[base + idx] = s_rf[wid][idx];
    __syncthreads();
    // mlp1: 4 samples x 128 channels = 512 outputs
    int sb0 = blockIdx.x * 4;
#pragma unroll
    for (int o = t; o < 512; o += 256) {
        int r = o >> 7, c = o & 127;
        float acc = sb[c];
#pragma unroll
        for (int k2 = 0; k2 < 28; ++k2)
            acc = fmaf(s_adf[r][k2], sW[k2 * 128 + c], acc);
        y_wb[c * 4096 + sb0 + r] = acc;
    }
}

// ---------------------------------------------------------------- batchnorm stats: block per channel
__global__ __launch_bounds__(256) void stats_kernel(
        const float* __restrict__ y,  // [C][4096]
        const float* __restrict__ g0, const float* __restrict__ be0,
        const float* __restrict__ g1, const float* __restrict__ be1, int csplit,
        float* __restrict__ scale, float* __restrict__ shift) {
    int c = blockIdx.x;
    const float* p = y + c * 4096;
    float s1 = 0.0f, s2 = 0.0f;
    for (int i = threadIdx.x; i < 4096; i += 256) {
        float v = p[i];
        s1 += v;
        s2 = fmaf(v, v, s2);
    }
    __shared__ float l1[256], l2[256];
    l1[threadIdx.x] = s1;
    l2[threadIdx.x] = s2;
    __syncthreads();
    for (int off = 128; off; off >>= 1) {
        if (threadIdx.x < off) {
            l1[threadIdx.x] += l1[threadIdx.x + off];
            l2[threadIdx.x] += l2[threadIdx.x + off];
        }
        __syncthreads();
    }
    if (threadIdx.x == 0) {
        float mean = l1[0] * (1.0f / 4096.0f);
        float var = l2[0] * (1.0f / 4096.0f) - mean * mean;
        float g = (c < csplit) ? g0[c] : g1[c - csplit];
        float be = (c < csplit) ? be0[c] : be1[c - csplit];
        float sc = g / sqrtf(var + 1e-5f);
        scale[c] = sc;
        shift[c] = be - mean * sc;
    }
}

// ---------------------------------------------------------------- mlp2 (float4 weight reads)
__global__ __launch_bounds__(256) void mlp2_kernel(
        const float* __restrict__ y_wb,
        const float* __restrict__ scale1, const float* __restrict__ shift1,
        const float* __restrict__ feature, const int* __restrict__ sidx,
        const float* __restrict__ adf,
        const float* __restrict__ Wo, const float* __restrict__ bo,
        float* __restrict__ y_o) {
    __shared__ float sW[92 * 128];
    __shared__ float t2[16 * 129];
    __shared__ float scat[16 * 92];
    int t = threadIdx.x;
    int s0 = blockIdx.x * 16;
    for (int i = t; i < 92 * 128; i += 256) sW[i] = Wo[i];
    for (int i = t; i < 16 * 128; i += 256) {
        int row = i & 15, c = i >> 4;
        t2[row * 129 + c] = fmaf(y_wb[c * 4096 + s0 + row], scale1[c], shift1[c]);
    }
    __syncthreads();
    for (int rr = 0; rr < 16; rr += 4) {
        int r = rr + (t >> 6);
        int c = t & 63;
        int si = sidx[s0 + r];
        float f = feature[si * 64 + c];
        float v = fmaf(f, t2[r * 129 + c], t2[r * 129 + 64 + c]);
        scat[r * 92 + c] = v >= 0.0f ? v : 0.2f * v;
    }
    for (int i = t; i < 16 * 28; i += 256) {
        int row = i / 28, k = i % 28;
        scat[row * 92 + 64 + k] = adf[(s0 + row) * 28 + k];
    }
    __syncthreads();
    int r = t >> 4, cg = t & 15;
    float acc[8];
#pragma unroll
    for (int j = 0; j < 8; ++j) acc[j] = bo[cg * 8 + j];
    for (int c = 0; c < 92; ++c) {
        float a = scat[r * 92 + c];
        float4 w0 = *(const float4*)&sW[c * 128 + cg * 8];
        float4 w1 = *(const float4*)&sW[c * 128 + cg * 8 + 4];
        acc[0] = fmaf(a, w0.x, acc[0]);
        acc[1] = fmaf(a, w0.y, acc[1]);
        acc[2] = fmaf(a, w0.z, acc[2]);
        acc[3] = fmaf(a, w0.w, acc[3]);
        acc[4] = fmaf(a, w1.x, acc[4]);
        acc[5] = fmaf(a, w1.y, acc[5]);
        acc[6] = fmaf(a, w1.z, acc[6]);
        acc[7] = fmaf(a, w1.w, acc[7]);
    }
    int s = s0 + r;
#pragma unroll
    for (int j = 0; j < 8; ++j) y_o[(cg * 8 + j) * 4096 + s] = acc[j];
}

// ---------------------------------------------------------------- final: per-channel stats + normalize + lrelu (validated in R10)
__global__ __launch_bounds__(256) void final_kernel(
        const float* __restrict__ y_o,
        const float* __restrict__ go, const float* __restrict__ betao,
        float* __restrict__ out_feat) {
    int j = blockIdx.x;
    const float* p = y_o + j * 4096;
    float s1 = 0.0f, s2 = 0.0f;
    for (int i = threadIdx.x; i < 4096; i += 256) {
        float v = p[i];
        s1 += v;
        s2 = fmaf(v, v, s2);
    }
    __shared__ float l1[256], l2[256];
    __shared__ float ssc, ssh;
    l1[threadIdx.x] = s1;
    l2[threadIdx.x] = s2;
    __syncthreads();
    for (int off = 128; off; off >>= 1) {
        if (threadIdx.x < off) {
            l1[threadIdx.x] += l1[threadIdx.x + off];
            l2[threadIdx.x] += l2[threadIdx.x + off];
        }
        __syncthreads();
    }
    if (threadIdx.x == 0) {
        float mean = l1[0] * (1.0f / 4096.0f);
        float var = l2[0] * (1.0f / 4096.0f) - mean * mean;
        float sc = go[j] / sqrtf(var + 1e-5f);
        ssc = sc;
        ssh = betao[j] - mean * sc;
    }
    __syncthreads();
    float sc = ssc, sh = ssh;
    for (int i = threadIdx.x; i < 4096; i += 256) {
        float v = fmaf(p[i], sc, sh);
        v = v >= 0.0f ? v : 0.2f * v;
        out_feat[i * 128 + j] = v;
    }
}

// ----------------------------------------------------------------
extern "C" void kernel_launch(void* const* d_in, const int* in_sizes, int n_in,
                              void* d_out, int out_size, void* d_ws, size_t ws_size,
                              hipStream_t stream) {
    const float* xyz = (const float*)d_in[0];
    const float* feature = (const float*)d_in[1];
    const int* sidx = (const int*)d_in[2];
    const float* Ww = (const float*)d_in[3];
    const float* bw = (const float*)d_in[4];
    const float* gw = (const float*)d_in[5];
    const float* betaw = (const float*)d_in[6];
    const float* Wb = (const float*)d_in[7];
    const float* bb = (const float*)d_in[8];
    const float* gb = (const float*)d_in[9];
    const float* betab = (const float*)d_in[10];
    const float* Wo = (const float*)d_in[11];
    const float* bo = (const float*)d_in[12];
    const float* go = (const float*)d_in[13];
    const float* betao = (const float*)d_in[14];

    float* out = (float*)d_out;
    float* out_xyz = out;                                  // 4096*3
    float* out_feat = out + 12288;                         // 4096*128
    float* out_rf = out + 12288 + 524288;                  // 4096*16*28
    float* out_ni = out + 12288 + 524288 + 1835008;        // 4096*16

    float* ws = (float*)d_ws;
    float4* cb = (float4*)ws;                  // 8192 float4
    float4* ca = (float4*)(ws + 32768);        // 4096 float4
    int* a_before = (int*)(ws + 49152);        // 4096*4
    float* intra_before = ws + 65536;          // 4096*6
    int* ni_i = (int*)(ws + 90112);            // 4096*16
    float* intra_after = ws + 155648;          // 4096*6
    float* adf = ws + 180224;                  // 4096*28
    float* y_wb = ws + 294912;                 // 128*4096
    float* y_o = ws + 819200;                  // 128*4096
    float* scale1 = ws + 1343488;              // 128
    float* shift1 = ws + 1343616;              // 128

    stage_kernel<<<32, 256, 0, stream>>>(xyz, sidx, cb, ca, out_xyz);
    knn_kernel<<<1024, 256, 0, stream>>>(cb, ca, sidx, a_before, intra_before,
                                         ni_i, intra_after, out_ni);
    asm_mlp1_kernel<<<1024, 256, 0, stream>>>(ca, cb, ni_i, intra_after, a_before,
                                              intra_before, sidx, Ww, bw, Wb, bb,
                                              out_rf, adf, y_wb);
    stats_kernel<<<128, 256, 0, stream>>>(y_wb, gw, betaw, gb, betab, 64, scale1, shift1);
    mlp2_kernel<<<256, 256, 0, stream>>>(y_wb, scale1, shift1, feature, sidx, adf, Wo, bo, y_o);
    final_kernel<<<128, 256, 0, stream>>>(y_o, go, betao, out_feat);
}